// Round 13
// baseline (194.248 us; speedup 1.0000x reference)
//
#include <hip/hip_runtime.h>

typedef __attribute__((ext_vector_type(8))) short short8;
typedef __attribute__((ext_vector_type(4))) float f32x4;

#define TPAD 100

__device__ __forceinline__ float bf2f(short s) {
  return __uint_as_float(((unsigned)(unsigned short)s) << 16);
}
__device__ __forceinline__ unsigned short f2bf(float f) {
  unsigned u = __float_as_uint(f);
  unsigned rounding = 0x7fffu + ((u >> 16) & 1u);
  return (unsigned short)((u + rounding) >> 16);
}

struct F8 { float4 a, b; };
__device__ __forceinline__ F8 ldf8(const float* p) {
  F8 r; r.a = *(const float4*)p; r.b = *(const float4*)(p + 4); return r;
}
__device__ __forceinline__ short8 cvtF8(F8 v) {
  short8 r;
  r[0]=(short)f2bf(v.a.x); r[1]=(short)f2bf(v.a.y); r[2]=(short)f2bf(v.a.z); r[3]=(short)f2bf(v.a.w);
  r[4]=(short)f2bf(v.b.x); r[5]=(short)f2bf(v.b.y); r[6]=(short)f2bf(v.b.z); r[7]=(short)f2bf(v.b.w);
  return r;
}

// Agent-coherent (sc1) stores: bypass local L2, globally visible after vmcnt
// drain. Used for ALL inter-phase buffers so sync needs no cache fences.
__device__ __forceinline__ void stg_f32(float* p, float v) {
  asm volatile("global_store_dword %0, %1, off sc1" :: "v"(p), "v"(v) : "memory");
}
__device__ __forceinline__ void stg_u16(unsigned short* p, unsigned short v) {
  unsigned w = v;
  asm volatile("global_store_short %0, %1, off sc1" :: "v"(p), "v"(w) : "memory");
}
__device__ __forceinline__ void stg_u32(unsigned* p, unsigned v) {
  asm volatile("global_store_dword %0, %1, off sc1" :: "v"(p), "v"(v) : "memory");
}

// ---------------- point-to-point flag sync ---------------------------------
// Flag index map (targets in parens):
//   F_ITER(sl,p) = sl*12+p   sl=0..7,p=0..11   (sl0:4, else 16)
//   F_TASK(t)    = 96+t      t=0..767          (1)   [single-i band tasks]
//   F_CHUNK(c)   = 864+c     c=0..47           (5)
//   F_L1(j)=912+j j=0..11 (2)   F_L2(j)=928+j j=0..2 (2)
#define NFLAGS 30688   // 959 flags * 32 u32
__device__ __forceinline__ void flag_spin(unsigned* f, unsigned tgt) {
  unsigned n = 0;
  while (__hip_atomic_load(f, __ATOMIC_RELAXED, __HIP_MEMORY_SCOPE_AGENT) < tgt) {
    __builtin_amdgcn_s_sleep(1);
    if (++n > 2000000u) break;   // ~0.3ms >> any legit wait (<100us)
  }
}
#define DRAIN() asm volatile("s_waitcnt vmcnt(0) lgkmcnt(0)" ::: "memory")
// kt-loop barrier (hgemm only): orders LDS ops; global prefetches stay in flight.
#define KTBAR() do { \
  asm volatile("s_waitcnt lgkmcnt(0)" ::: "memory"); \
  __builtin_amdgcn_s_barrier(); \
  __builtin_amdgcn_sched_barrier(0); \
} while (0)

// Shared-memory union across phases (max = t4: 115,232 B; 1 blk/CU).
union __align__(16) SmemU {
  struct { unsigned short As[2][64][72]; unsigned short Ws[2][64][72]; float Cs[64][64]; } g;  // hgemm
  struct { unsigned short As8[8][64][72]; float Cs[64][64]; } gi;                              // iter
  struct { unsigned short rows[8][264]; float sred[96]; float smu; } bn;                       // band
  struct { float Ms[96 * TPAD]; float Pc[2][96 * TPAD]; float red[8]; } t4;                    // tree4
  struct { float Qs[2][96 * TPAD]; float vv[4][96]; float red[8]; float redm[4]; } f;          // final
};

// ---------------- prep: combined bias + flag zeroing (tiny) ----------------
__global__ void prep_kernel(const float* __restrict__ bl, const float* __restrict__ br,
                            const float* __restrict__ bgl, const float* __restrict__ bgr,
                            float* __restrict__ bc, unsigned* __restrict__ flags)
{
  int idx = blockIdx.x * 256 + threadIdx.x;
  if (idx < 1024) {
    bc[idx] = (idx < 256) ? bl[idx] + br[idx] : bgl[idx-256] + bgr[idx-256];
  } else {
    int j = idx - 1024;
    if (j < NFLAGS) flags[j] = 0u;
  }
}

// ---------------- tree4: Tout[j] = ~T[4j+3]·~T[4j+2]·~T[4j+1]·~T[4j] -------
// Slice-sequential: block keeps a 96x48 column slice P and left-multiplies by
// each (max-normalized) factor in turn. Normalization factors are computed
// from the FULL factor with a deterministic reduction, so both slice-blocks
// of output j agree. logsum accumulates Cin + log(max) per factor.
__device__ __forceinline__ void tree4(SmemU& sm,
    const float* Tin, const float* Cin, float* Tout, float* Cout, int j, int cs)
{
  const int tid = threadIdx.x;
  const int wv = tid >> 6, lane = tid & 63;
  const int tr = tid >> 4, tc = tid & 15;
  const int r0 = tr * 6, c0 = tc * 3;
  float logsum = Cin[4*j] + Cin[4*j+1] + Cin[4*j+2] + Cin[4*j+3];
  float acc[6][3];
  int cur = 0;
  #pragma unroll
  for (int s = 0; s < 4; ++s) {
    float4 mv[9];
    const float* mp = Tin + (size_t)(4*j + s) * 9216 + tid*36;
    #pragma unroll
    for (int q = 0; q < 9; ++q) mv[q] = *(const float4*)(mp + q*4);
    float mx = 0.f;
    #pragma unroll
    for (int q = 0; q < 9; ++q)
      mx = fmaxf(mx, fmaxf(fmaxf(mv[q].x, mv[q].y), fmaxf(mv[q].z, mv[q].w)));
    #pragma unroll
    for (int off = 32; off; off >>= 1) mx = fmaxf(mx, __shfl_down(mx, off));
    if (lane == 0) sm.t4.red[(s & 1)*4 + wv] = mx;
    __syncthreads();   // S1: prior Ms reads / Pc writes complete; red ready
    {
      const float* rd = &sm.t4.red[(s & 1)*4];
      mx = fmaxf(fmaxf(rd[0], rd[1]), fmaxf(rd[2], rd[3]));
    }
    float inv = 1.0f / mx;
    logsum += __logf(mx);
    if (s == 0) {
      // store normalized col-slice into Pc[0] (col-major)
      #pragma unroll
      for (int q = 0; q < 9; ++q) {
        int e = tid*36 + q*4;
        int r = e / 96, k = e - r*96;
        float vals[4] = {mv[q].x, mv[q].y, mv[q].z, mv[q].w};
        #pragma unroll
        for (int x = 0; x < 4; ++x) {
          int cl = k + x - cs;
          if ((unsigned)cl < 48u) sm.t4.Pc[0][cl*TPAD + r] = vals[x] * inv;
        }
      }
      __syncthreads();   // S2: Pc[0] ready
    } else {
      // store normalized full factor into Ms (row-major)
      #pragma unroll
      for (int q = 0; q < 9; ++q) {
        int e = tid*36 + q*4;
        int r = e / 96, k = e - r*96;
        float4 m = mv[q];
        m.x *= inv; m.y *= inv; m.z *= inv; m.w *= inv;
        *(float4*)&sm.t4.Ms[r*TPAD + k] = m;
      }
      __syncthreads();   // S2: Ms + Pc[cur] ready
      #pragma unroll
      for (int i = 0; i < 6; ++i)
        #pragma unroll
        for (int m = 0; m < 3; ++m) acc[i][m] = 0.f;
      for (int k = 0; k < 96; k += 4) {
        float4 p0 = *(const float4*)&sm.t4.Pc[cur][(c0+0)*TPAD + k];
        float4 p1 = *(const float4*)&sm.t4.Pc[cur][(c0+1)*TPAD + k];
        float4 p2 = *(const float4*)&sm.t4.Pc[cur][(c0+2)*TPAD + k];
        #pragma unroll
        for (int i = 0; i < 6; ++i) {
          float4 b = *(const float4*)&sm.t4.Ms[(r0+i)*TPAD + k];
          acc[i][0] += b.x*p0.x + b.y*p0.y + b.z*p0.z + b.w*p0.w;
          acc[i][1] += b.x*p1.x + b.y*p1.y + b.z*p1.z + b.w*p1.w;
          acc[i][2] += b.x*p2.x + b.y*p2.y + b.z*p2.z + b.w*p2.w;
        }
      }
      if (s < 3) {
        #pragma unroll
        for (int i = 0; i < 6; ++i)
          #pragma unroll
          for (int m = 0; m < 3; ++m)
            sm.t4.Pc[cur ^ 1][(c0+m)*TPAD + (r0+i)] = acc[i][m];
        cur ^= 1;
        // no sync needed here: next factor's S1 covers the hazards
      }
    }
  }
  float* op = Tout + (size_t)j * 9216;
  #pragma unroll
  for (int i = 0; i < 6; ++i)
    #pragma unroll
    for (int m = 0; m < 3; ++m)
      stg_f32(&op[(size_t)(r0+i)*96 + cs + c0 + m], acc[i][m]);
  if (cs == 0 && tid == 0) stg_f32(&Cout[j], logsum);
}

// ---------------- mega kernel: flag-pipelined phase graph ------------------
__global__ __launch_bounds__(256, 1) void mega_kernel(
    const float* feats, const float* Wd, const float* bd,
    const float* Wl, const float* Wr, const float* Gl, const float* Gr,
    const float* bc,
    unsigned short* ht, const float* Wt, const float* bt,
    float* Bband, float* Xn, float* muv, const float* trans,
    const int* tags,
    float* T0, float* T1, float* T2,
    float* C0, float* C1, float* C2,
    float* out, unsigned* flags)
{
  __shared__ SmemU sm;
  const int bid = blockIdx.x;
  const int tid = threadIdx.x;
  const int wave = tid >> 6, lane = tid & 63;

  if (bid < 192) {
    const int p = bid % 12;
    const int lr = tid >> 3;
    const int c8 = (tid & 7) * 8;
    const int q8 = (lane >> 4) * 8;
    // ============ phase: hgemm (48 blocks; f32 inputs, cvt on the fly) =====
    if (bid < 48) {
      const int p0 = p * 64;
      const int n0 = (bid / 12) * 64;
      f32x4 acc[4];
      #pragma unroll
      for (int i = 0; i < 4; ++i)
        #pragma unroll
        for (int j = 0; j < 4; ++j) acc[i][j] = 0.f;
      F8 fa0[2], fa1[2], fw0[2], fw1[2];
      #pragma unroll
      for (int q = 0; q < 2; ++q) {
        int kb = q * 64;
        fa0[q] = ldf8(feats + (size_t)(p0 + lr)*512 + kb + c8);
        fa1[q] = ldf8(feats + (size_t)(p0 + lr + 32)*512 + kb + c8);
        fw0[q] = ldf8(Wd + (size_t)(n0 + lr)*512 + kb + c8);
        fw1[q] = ldf8(Wd + (size_t)(n0 + lr + 32)*512 + kb + c8);
      }
      #pragma unroll
      for (int kt = 0; kt < 8; ++kt) {
        const int sb = kt & 1;
        *(short8*)(&sm.g.As[sb][lr][c8])      = cvtF8(fa0[sb]);
        *(short8*)(&sm.g.As[sb][lr + 32][c8]) = cvtF8(fa1[sb]);
        *(short8*)(&sm.g.Ws[sb][lr][c8])      = cvtF8(fw0[sb]);
        *(short8*)(&sm.g.Ws[sb][lr + 32][c8]) = cvtF8(fw1[sb]);
        if (kt < 6) {
          int kb = (kt + 2) * 64;
          fa0[sb] = ldf8(feats + (size_t)(p0 + lr)*512 + kb + c8);
          fa1[sb] = ldf8(feats + (size_t)(p0 + lr + 32)*512 + kb + c8);
          fw0[sb] = ldf8(Wd + (size_t)(n0 + lr)*512 + kb + c8);
          fw1[sb] = ldf8(Wd + (size_t)(n0 + lr + 32)*512 + kb + c8);
        }
        KTBAR();
        #pragma unroll
        for (int kk = 0; kk < 2; ++kk) {
          short8 bfr = *(const short8*)(&sm.g.Ws[sb][wave*16 + (lane & 15)][kk*32 + q8]);
          #pragma unroll
          for (int mt = 0; mt < 4; ++mt) {
            short8 afr = *(const short8*)(&sm.g.As[sb][mt*16 + (lane & 15)][kk*32 + q8]);
            acc[mt] = __builtin_amdgcn_mfma_f32_16x16x32_bf16(afr, bfr, acc[mt], 0, 0, 0);
          }
        }
        KTBAR();   // all waves done reading buffer sb before it is overwritten
      }
      int o = n0 + wave*16 + (lane & 15);
      float bias = bd[o];
      #pragma unroll
      for (int mt = 0; mt < 4; ++mt)
        #pragma unroll
        for (int r = 0; r < 4; ++r) {
          int row = p0 + mt*16 + (lane >> 4)*4 + r;
          stg_u16(&ht[row*256 + o], f2bf(acc[mt][r] + bias));
        }
      DRAIN();
      __syncthreads();
      if (tid == 0) atomicAdd(&flags[(0*12 + p)*32], 1u);
    }

    // ============ 7 span iterations: W direct from f32 inputs (no WcB!) ====
    const int p0 = p * 64;
    const int n0i = (bid / 12) * 16;
    short8 wfrag[16];
    {
      const int o = wave*256 + n0i + (lane & 15);   // Wc row: gate*256 + d
      const float* b0 = (o < 256) ? (Wl + (size_t)o*256) : (Gl + (size_t)(o-256)*256);
      const float* b1 = (o < 256) ? (Wr + (size_t)o*256) : (Gr + (size_t)(o-256)*256);
      #pragma unroll
      for (int kt = 0; kt < 4; ++kt)
        #pragma unroll
        for (int kk = 0; kk < 2; ++kk)
          wfrag[kt*2 + kk] = cvtF8(ldf8(b0 + kt*64 + kk*32 + q8));
      #pragma unroll
      for (int kt = 4; kt < 8; ++kt)
        #pragma unroll
        for (int kk = 0; kk < 2; ++kk)
          wfrag[kt*2 + kk] = cvtF8(ldf8(b1 + (kt-4)*64 + kk*32 + q8));
    }
    for (int sl = 1; sl <= 7; ++sl) {
      unsigned tgt = (sl == 1) ? 4u : 16u;
      if (tid == 0) flag_spin(&flags[((sl-1)*12 + p)*32], tgt);
      __syncthreads();                          // tile p ready
      const unsigned short* htp = ht + (size_t)(sl - 1) * 196608;
      unsigned short* htn = ht + (size_t)sl * 196608;
      const int Mvalid = 768 - sl;
      short8 areg[16];
      // kt 0..3 (shift=0): rows p0..p0+63, tile p ONLY -> load while thread
      // 64 concurrently waits for tile p+1 (split-wait overlap).
      #pragma unroll
      for (int kt = 0; kt < 4; ++kt) {
        const int kcol = kt * 64;
        areg[kt*2]     = *(const short8*)(htp + (size_t)(p0 + lr)*256 + kcol + c8);
        areg[kt*2 + 1] = *(const short8*)(htp + (size_t)(p0 + lr + 32)*256 + kcol + c8);
      }
      if (tid == 64 && p < 11) flag_spin(&flags[((sl-1)*12 + p + 1)*32], tgt);
      #pragma unroll
      for (int kt = 0; kt < 4; ++kt) {
        *(short8*)(&sm.gi.As8[kt][lr][c8])      = areg[kt*2];
        *(short8*)(&sm.gi.As8[kt][lr + 32][c8]) = areg[kt*2 + 1];
      }
      __syncthreads();                          // p+1 ready AND kt0..3 staged
      // kt 4..7 (shift=1): rows p0+1..p0+64 (touches tile p+1's first row).
      #pragma unroll
      for (int kt = 4; kt < 8; ++kt) {
        const int kcol = (kt & 3) * 64;
        int g0 = p0 + lr + 1;      if (g0 > 767) g0 = 767;
        int g1 = p0 + lr + 33;     if (g1 > 767) g1 = 767;
        areg[kt*2]     = *(const short8*)(htp + (size_t)g0*256 + kcol + c8);
        areg[kt*2 + 1] = *(const short8*)(htp + (size_t)g1*256 + kcol + c8);
      }
      #pragma unroll
      for (int kt = 4; kt < 8; ++kt) {
        *(short8*)(&sm.gi.As8[kt][lr][c8])      = areg[kt*2];
        *(short8*)(&sm.gi.As8[kt][lr + 32][c8]) = areg[kt*2 + 1];
      }
      __syncthreads();
      // MFMA sweep: no barriers, compiler-scheduled lgkmcnt only.
      f32x4 acc[4];
      #pragma unroll
      for (int i = 0; i < 4; ++i)
        #pragma unroll
        for (int j = 0; j < 4; ++j) acc[i][j] = 0.f;
      #pragma unroll
      for (int kt = 0; kt < 8; ++kt) {
        #pragma unroll
        for (int kk = 0; kk < 2; ++kk) {
          #pragma unroll
          for (int mt = 0; mt < 4; ++mt) {
            short8 afr = *(const short8*)(&sm.gi.As8[kt][mt*16 + (lane & 15)][kk*32 + q8]);
            acc[mt] = __builtin_amdgcn_mfma_f32_16x16x32_bf16(afr, wfrag[kt*2 + kk], acc[mt], 0, 0, 0);
          }
        }
      }
      #pragma unroll
      for (int mt = 0; mt < 4; ++mt)
        #pragma unroll
        for (int r = 0; r < 4; ++r)
          sm.gi.Cs[mt*16 + (lane >> 4)*4 + r][wave*16 + (lane & 15)] = acc[mt][r];
      __syncthreads();

      // epilogue: 2 adjacent d-cols per thread, packed u32 stores
      {
        int dl = tid & 7;
        int d0 = n0i + dl*2;
        int cc0 = dl*2;
        float bz0 = bc[d0],       bz1 = bc[d0+1];
        float b00 = bc[256 + d0], b01 = bc[256 + d0 + 1];
        float b10 = bc[512 + d0], b11 = bc[512 + d0 + 1];
        float b20 = bc[768 + d0], b21 = bc[768 + d0 + 1];
        for (int pr = tid >> 3; pr < 64; pr += 32) {
          int pw = p0 + pr;
          if (pw >= Mvalid) continue;
          float z0 = sm.gi.Cs[pr][cc0]      + bz0, z1 = sm.gi.Cs[pr][cc0+1]      + bz1;
          float g00 = sm.gi.Cs[pr][16+cc0]  + b00, g01 = sm.gi.Cs[pr][16+cc0+1]  + b01;
          float g10 = sm.gi.Cs[pr][32+cc0]  + b10, g11 = sm.gi.Cs[pr][32+cc0+1]  + b11;
          float g20 = sm.gi.Cs[pr][48+cc0]  + b20, g21 = sm.gi.Cs[pr][48+cc0+1]  + b21;
          unsigned lv = *(const unsigned*)(htp + (size_t)pw*256 + d0);
          unsigned rv = *(const unsigned*)(htp + (size_t)(pw+1)*256 + d0);
          float l0 = bf2f((short)(lv & 0xffff)), l1 = bf2f((short)(lv >> 16));
          float r0v = bf2f((short)(rv & 0xffff)), r1v = bf2f((short)(rv >> 16));
          float hh0 = 4.f / (1.f + __expf(-z0)) - 2.f;
          float hh1 = 4.f / (1.f + __expf(-z1)) - 2.f;
          float mg0 = fmaxf(g00, fmaxf(g10, g20));
          float mg1 = fmaxf(g01, fmaxf(g11, g21));
          float e00 = __expf(g00 - mg0), e10 = __expf(g10 - mg0), e20 = __expf(g20 - mg0);
          float e01 = __expf(g01 - mg1), e11 = __expf(g11 - mg1), e21 = __expf(g21 - mg1);
          float o0 = (e00*hh0 + e10*l0 + e20*r0v) / (e00 + e10 + e20);
          float o1 = (e01*hh1 + e11*l1 + e21*r1v) / (e01 + e11 + e21);
          unsigned pack = (unsigned)f2bf(o0) | ((unsigned)f2bf(o1) << 16);
          stg_u32((unsigned*)(htn + (size_t)pw*256 + d0), pack);
        }
      }
      DRAIN();
      __syncthreads();
      if (tid == 0) atomicAdd(&flags[(sl*12 + p)*32], 1u);
    }
  }

  // ============ phase: band (768 single-i tasks; 3 per block max) ===========
  for (int i1 = bid; i1 < 768; i1 += 256) {
    const int i = i1 + 1;   // 1..768
    if (tid < 2) {
      int rlo = i - 8; if (rlo < 0) rlo = 0;
      int tlo = rlo >> 6, thi = (i - 1) >> 6;
      int tt = (tid == 0) ? tlo : thi;
      flag_spin(&flags[(7*12 + tt)*32], 16u);
    }
    __syncthreads();
    {
      int k = tid >> 5, cc = (tid & 31) * 8;
      int pr = i - 8 + k;
      short8 v;
      if (pr >= 0) {
        int slx = 7 - k;
        v = *(const short8*)(ht + ((size_t)slx*768 + pr)*256 + cc);
      } else {
        #pragma unroll
        for (int j = 0; j < 8; ++j) v[j] = 0;
      }
      *(short8*)(&sm.bn.rows[k][cc]) = v;
    }
    __syncthreads();
    float res = -1e30f;
    if (tid < 96) {
      int t = tid >> 3, k = tid & 7;
      int pr = i - 8 + k;
      if (pr >= 0) {
        float acc = 0.f;
        for (int dch = 0; dch < 256; dch += 8) {
          float4 wa = *(const float4*)(Wt + t*256 + dch);
          float4 wb = *(const float4*)(Wt + t*256 + dch + 4);
          short8 hv = *(const short8*)(&sm.bn.rows[k][dch]);
          acc += wa.x*bf2f(hv[0]) + wa.y*bf2f(hv[1]) + wa.z*bf2f(hv[2]) + wa.w*bf2f(hv[3])
               + wb.x*bf2f(hv[4]) + wb.y*bf2f(hv[5]) + wb.z*bf2f(hv[6]) + wb.w*bf2f(hv[7]);
        }
        res = acc + bt[t];
      }
      stg_f32(&Bband[(size_t)i*96 + tid], res);
      sm.bn.sred[tid] = res;
    }
    __syncthreads();
    if (tid < 32) {
      float m = fmaxf(sm.bn.sred[tid], fmaxf(sm.bn.sred[tid+32], sm.bn.sred[tid+64]));
      #pragma unroll
      for (int off = 16; off; off >>= 1) m = fmaxf(m, __shfl_down(m, off));
      if (tid == 0) { stg_f32(&muv[i], m); sm.bn.smu = m; }
    }
    __syncthreads();
    if (tid < 96) stg_f32(&Xn[(size_t)i*96 + tid], __expf(res - sm.bn.smu));
    DRAIN();
    __syncthreads();
    if (tid == 0) atomicAdd(&flags[(96 + i1)*32], 1u);
  }
  if (bid >= 240) return;

  // ============ phase: chunkT (240 blocks; 5 per chunk) ============
  {
    const int chunk = bid / 5;
    const int bxx = bid % 5;
    if (tid < 16) flag_spin(&flags[(96 + 16*chunk + tid)*32], 1u);
    __syncthreads();
    if (bxx == 0 && tid == 0) stg_f32(&C0[chunk], 0.f);
    const int a = chunk * 16;
    const int g = lane / 12;
    const int t = lane - g * 12;
    const int cidx = bxx * 20 + wave * 5 + g;
    const bool active = (g < 5) && (cidx < 96);
    const int c = active ? cidx : 95;
    const int s = c / 12, tau = c - s * 12;
    float Etc[12];
    #pragma unroll
    for (int jj = 0; jj < 12; ++jj) Etc[jj] = __expf(trans[jj*12 + t]);
    float NA[8], V[8];
    #pragma unroll
    for (int jj = 0; jj < 8; ++jj) { NA[jj] = 0.f; V[jj] = 0.f; }
    #pragma unroll
    for (int jj = 0; jj < 8; ++jj) if (jj == s) {
      NA[jj] = (t == tau) ? 1.f : 0.f;
      V[jj]  = Etc[tau];
    }
    const int gbb = (g * 12) * 4;
    #pragma unroll
    for (int m = 1; m <= 16; ++m) {
      const float* xr = Xn + (size_t)(a + m) * 96 + t * 8;
      float4 x0 = *(const float4*)xr;
      float4 x1 = *(const float4*)(xr + 4);
      float sf = __expf(-muv[a + m]);
      float na = x0.x*V[0] + x0.y*V[1] + x0.z*V[2] + x0.w*V[3]
               + x1.x*V[4] + x1.y*V[5] + x1.z*V[6] + x1.w*V[7];
      int nai = __float_as_int(na);
      float nb[12];
      #pragma unroll
      for (int jj = 0; jj < 12; ++jj)
        nb[jj] = __int_as_float(__builtin_amdgcn_ds_bpermute(gbb + jj*4, nai));
      float pp0 = nb[0]*Etc[0] + nb[1]*Etc[1] + nb[2]*Etc[2]   + nb[3]*Etc[3];
      float pp1 = nb[4]*Etc[4] + nb[5]*Etc[5] + nb[6]*Etc[6]   + nb[7]*Etc[7];
      float pp2 = nb[8]*Etc[8] + nb[9]*Etc[9] + nb[10]*Etc[10] + nb[11]*Etc[11];
      float v = (pp0 + pp1) + pp2;
      #pragma unroll
      for (int kq = 0; kq < 7; ++kq) { NA[kq] = NA[kq+1]*sf; V[kq] = V[kq+1]*sf; }
      NA[7] = na; V[7] = v;
    }
    if (active) {
      float* dst = T0 + (size_t)chunk * 9216 + c;
      #pragma unroll
      for (int jj = 0; jj < 8; ++jj) stg_f32(&dst[(size_t)(jj*12 + t) * 96], NA[jj]);
    }
    DRAIN();
    __syncthreads();
    if (tid == 0) atomicAdd(&flags[(864 + chunk)*32], 1u);
  }
  if (bid >= 24) return;

  // ============ tree: 2 levels of 4-way products (48 -> 12 -> 3) ============
  {
    int j = bid >> 1, cs = (bid & 1) * 48;
    if (tid < 4) flag_spin(&flags[(864 + 4*j + tid)*32], 5u);
    __syncthreads();
    tree4(sm, T0, C0, T1, C1, j, cs);    // 48 -> 12
    DRAIN(); __syncthreads();
    if (tid == 0) atomicAdd(&flags[(912 + j)*32], 1u);
  }
  if (bid >= 6) return;
  {
    int j = bid >> 1, cs = (bid & 1) * 48;
    if (tid < 4) flag_spin(&flags[(912 + 4*j + tid)*32], 2u);
    __syncthreads();
    tree4(sm, T1, C1, T2, C2, j, cs);    // 12 -> 3
    DRAIN(); __syncthreads();
    if (tid == 0) atomicAdd(&flags[(928 + j)*32], 1u);
  }
  if (bid) return;

  // ============ phase: final (block 0) ============
  {
    if (tid < 3) flag_spin(&flags[(928 + tid)*32], 2u);
    __syncthreads();
    float4 P[9];
    const float* p0p = T2 + tid * 36;
    #pragma unroll
    for (int q = 0; q < 9; ++q) P[q] = *(const float4*)(p0p + q*4);

    float gold = 0.f;
    if (tid < 96) {
      int a = tags[tid*4+0], b = tags[tid*4+1], cc = tags[tid*4+2], d = tags[tid*4+3];
      float v = trans[cc*12 + d];
      int sl = b - a;
      if (sl >= 0 && sl < 8) v += Bband[(size_t)(b+1)*96 + d*8 + (7 - sl)];
      else v += bt[d];
      gold = v;
    }
    float mp = 0.f;
    for (int q = tid; q < 768; q += 256) mp += muv[1 + q];
    #pragma unroll
    for (int off = 32; off; off >>= 1) {
      gold += __shfl_down(gold, off);
      mp   += __shfl_down(mp, off);
    }
    if (lane == 0) { sm.f.red[wave] = gold; sm.f.red[4 + wave] = mp; }

    #pragma unroll
    for (int q = 0; q < 9; ++q) {
      int e = tid*36 + q*4;
      int r = e / 96, k = e - r*96;
      *(float4*)&sm.f.Qs[0][r*TPAD + k] = P[q];
    }
    if (tid < 96) sm.f.vv[0][tid] = (tid == 94) ? 1.f : 0.f;  // onehot(START=84+10)
    __syncthreads();
    float gold_t = sm.f.red[0] + sm.f.red[1] + sm.f.red[2] + sm.f.red[3];
    float musum  = sm.f.red[4] + sm.f.red[5] + sm.f.red[6] + sm.f.red[7];
    float Ct = C2[0] + C2[1] + C2[2];

    #pragma unroll
    for (int s = 0; s < 3; ++s) {
      if (s < 2) {                       // prefetch next matrix during matvec
        const float* pn = T2 + (size_t)(s+1)*9216 + tid*36;
        #pragma unroll
        for (int q = 0; q < 9; ++q) P[q] = *(const float4*)(pn + q*4);
      }
      float acc = 0.f;
      if (tid < 96) {
        const float* Qr = &sm.f.Qs[s & 1][tid * TPAD];
        #pragma unroll
        for (int k = 0; k < 96; k += 4) {
          float4 qv = *(const float4*)(Qr + k);
          float4 zv = *(const float4*)&sm.f.vv[s][k];
          acc += qv.x*zv.x + qv.y*zv.y + qv.z*zv.z + qv.w*zv.w;
        }
      }
      float am = (tid < 96) ? acc : 0.f;
      #pragma unroll
      for (int off = 32; off; off >>= 1) am = fmaxf(am, __shfl_down(am, off));
      if (lane == 0) sm.f.redm[wave] = am;
      __syncthreads();
      float mx = fmaxf(fmaxf(sm.f.redm[0], sm.f.redm[1]), fmaxf(sm.f.redm[2], sm.f.redm[3]));
      Ct += __logf(mx);
      if (tid < 96) sm.f.vv[s+1][tid] = acc / mx;
      if (s < 2) {
        #pragma unroll
        for (int q = 0; q < 9; ++q) {
          int e = tid*36 + q*4;
          int r = e / 96, k = e - r*96;
          *(float4*)&sm.f.Qs[(s+1)&1][r*TPAD + k] = P[q];
        }
      }
      __syncthreads();
    }
    if (tid == 0) {
      float lsum = 0.f;
      #pragma unroll
      for (int t = 0; t < 11; ++t) lsum += __logf(sm.f.vv[3][84 + t]);
      out[0] = lsum + 11.f * (Ct + musum) - gold_t;
    }
  }
}

// ---------------------------------------------------------------------------
extern "C" void kernel_launch(void* const* d_in, const int* in_sizes, int n_in,
                              void* d_out, int out_size, void* d_ws, size_t ws_size,
                              hipStream_t stream)
{
  const float* feats = (const float*)d_in[0];
  const int*   tags  = (const int*)  d_in[1];
  const float* Wd    = (const float*)d_in[2];
  const float* bd    = (const float*)d_in[3];
  const float* Wl    = (const float*)d_in[4];
  const float* bl    = (const float*)d_in[5];
  const float* Wr    = (const float*)d_in[6];
  const float* br    = (const float*)d_in[7];
  const float* Gl    = (const float*)d_in[8];
  const float* bgl   = (const float*)d_in[9];
  const float* Gr    = (const float*)d_in[10];
  const float* bgr   = (const float*)d_in[11];
  const float* Wt    = (const float*)d_in[12];
  const float* bt    = (const float*)d_in[13];
  const float* trans = (const float*)d_in[14];
  float* out = (float*)d_out;

  // Workspace layout: every buffer below is written exactly once inside the
  // mega kernel (with sc1 stores) and never read before written. No overlays.
  char* ws = (char*)d_ws;
  float*          bc     = (float*)         (ws + 2097152);  // 1024 f32
  unsigned short* ht     = (unsigned short*)(ws + 2101248);  // 8*768*256 bf16
  float*          Bband  = (float*)         (ws + 5246976);  // 769*96 f32
  float*          Xn     = (float*)         (ws + 5542272);  // 769*96 f32
  float*          muv    = (float*)         (ws + 5837568);  // 769 f32
  float*          T0     = (float*)         (ws + 5841664);  // 48*9216 f32
  float*          T1     = (float*)         (ws + 7611136);  // 12*9216 f32
  float*          T2     = (float*)         (ws + 8495872);  //  3*9216 f32
  float*          C0     = (float*)         (ws + 9270016);  // 48 f32
  float*          C1     = (float*)         (ws + 9270272);  // 12 f32
  float*          C2     = (float*)         (ws + 9270528);  //  3 f32
  unsigned*       flags  = (unsigned*)      (ws + 9271296);  // 959 flags x 32 u32

  prep_kernel<<<124, 256, 0, stream>>>(bl, br, bgl, bgr, bc, flags);
  mega_kernel<<<256, 256, 0, stream>>>(feats, Wd, bd, Wl, Wr, Gl, Gr, bc,
                                       ht, Wt, bt, Bband, Xn, muv, trans, tags,
                                       T0, T1, T2, C0, C1, C2,
                                       out, flags);
}

// Round 14
// 192.860 us; speedup vs baseline: 1.0072x; 1.0072x over previous
//
#include <hip/hip_runtime.h>

typedef __attribute__((ext_vector_type(8))) short short8;
typedef __attribute__((ext_vector_type(4))) float f32x4;

#define TPAD 100

__device__ __forceinline__ float bf2f(short s) {
  return __uint_as_float(((unsigned)(unsigned short)s) << 16);
}
__device__ __forceinline__ unsigned short f2bf(float f) {
  unsigned u = __float_as_uint(f);
  unsigned rounding = 0x7fffu + ((u >> 16) & 1u);
  return (unsigned short)((u + rounding) >> 16);
}

struct F8 { float4 a, b; };
__device__ __forceinline__ F8 ldf8(const float* p) {
  F8 r; r.a = *(const float4*)p; r.b = *(const float4*)(p + 4); return r;
}
__device__ __forceinline__ short8 cvtF8(F8 v) {
  short8 r;
  r[0]=(short)f2bf(v.a.x); r[1]=(short)f2bf(v.a.y); r[2]=(short)f2bf(v.a.z); r[3]=(short)f2bf(v.a.w);
  r[4]=(short)f2bf(v.b.x); r[5]=(short)f2bf(v.b.y); r[6]=(short)f2bf(v.b.z); r[7]=(short)f2bf(v.b.w);
  return r;
}

// Agent-coherent (sc1) stores: bypass local L2, globally visible after vmcnt
// drain. Used for ALL inter-phase buffers so sync needs no cache fences.
__device__ __forceinline__ void stg_f32(float* p, float v) {
  asm volatile("global_store_dword %0, %1, off sc1" :: "v"(p), "v"(v) : "memory");
}
__device__ __forceinline__ void stg_u16(unsigned short* p, unsigned short v) {
  unsigned w = v;
  asm volatile("global_store_short %0, %1, off sc1" :: "v"(p), "v"(w) : "memory");
}
__device__ __forceinline__ void stg_u32(unsigned* p, unsigned v) {
  asm volatile("global_store_dword %0, %1, off sc1" :: "v"(p), "v"(v) : "memory");
}

// ---------------- point-to-point flag sync ---------------------------------
// Flag index map (targets in parens):
//   F_ITER(sl,p) = sl*12+p   sl=0..7,p=0..11   (sl0:4, else 16)
//   F_TASK(t)    = 96+t      t=0..767          (1)   [single-i band tasks]
//   F_CHUNK(c)   = 864+c     c=0..47           (5)
//   F_T1(j)=912+j(2) F_T2(j)=936+j(2) F_T3(j)=948+j(2) F_T4(j)=954+j(2)
//   FWCB = 958 (208)  -- WcB conversion done
#define NFLAGS 30688   // 959 flags * 32 u32
__device__ __forceinline__ void flag_spin(unsigned* f, unsigned tgt) {
  unsigned n = 0;
  while (__hip_atomic_load(f, __ATOMIC_RELAXED, __HIP_MEMORY_SCOPE_AGENT) < tgt) {
    __builtin_amdgcn_s_sleep(1);
    if (++n > 2000000u) break;   // ~0.3ms >> any legit wait (<100us)
  }
}
#define DRAIN() asm volatile("s_waitcnt vmcnt(0) lgkmcnt(0)" ::: "memory")
// kt-loop barrier (hgemm only): orders LDS ops; global prefetches stay in flight.
#define KTBAR() do { \
  asm volatile("s_waitcnt lgkmcnt(0)" ::: "memory"); \
  __builtin_amdgcn_s_barrier(); \
  __builtin_amdgcn_sched_barrier(0); \
} while (0)

// Shared-memory union across phases (max = iter: As8+Cs = 90,112 B; 1 blk/CU).
union __align__(16) SmemU {
  struct { unsigned short As[2][64][72]; unsigned short Ws[2][64][72]; float Cs[64][64]; } g;  // hgemm
  struct { unsigned short As8[8][64][72]; float Cs[64][64]; } gi;                              // iter
  struct { unsigned short rows[8][264]; float sred[96]; float smu; } bn;                       // band
  struct { float Bs[96 * TPAD]; float Acs[96 * TPAD]; float red[8]; } t;                       // treemul
  struct { float Qs[2][96 * TPAD]; float vv[4][96]; float red[8]; float redm[4]; } f;          // final
};

// ---------------- prep: combined bias + flag zeroing (tiny) ----------------
__global__ void prep_kernel(const float* __restrict__ bl, const float* __restrict__ br,
                            const float* __restrict__ bgl, const float* __restrict__ bgr,
                            float* __restrict__ bc, unsigned* __restrict__ flags)
{
  int idx = blockIdx.x * 256 + threadIdx.x;
  if (idx < 1024) {
    bc[idx] = (idx < 256) ? bl[idx] + br[idx] : bgl[idx-256] + bgr[idx-256];
  } else {
    int j = idx - 1024;
    if (j < NFLAGS) flags[j] = 0u;
  }
}

// ---------------- tree level (device fn): Tout[j] = norm(Tin[2j+1])*norm(Tin[2j])
__device__ __forceinline__ void treelevel(SmemU& sm,
    const float* Tin, const float* Cin, float* Tout, float* Cout)
{
  const int bid = blockIdx.x;
  const int tid = threadIdx.x;
  const int wv = tid >> 6, lane = tid & 63;
  const int j = bid >> 1;
  const int cs = (bid & 1) * 48;
  const float* Ag = Tin + (size_t)(2*j) * 9216;      // applied first
  const float* Bg = Tin + (size_t)(2*j + 1) * 9216;  // applied second

  float4 av[9], bv[9];
  const float* ap = Ag + tid * 36;
  const float* bp = Bg + tid * 36;
  #pragma unroll
  for (int q = 0; q < 9; ++q) av[q] = *(const float4*)(ap + q*4);
  #pragma unroll
  for (int q = 0; q < 9; ++q) bv[q] = *(const float4*)(bp + q*4);
  float ma = 0.f, mb = 0.f;
  #pragma unroll
  for (int q = 0; q < 9; ++q) {
    ma = fmaxf(ma, fmaxf(fmaxf(av[q].x, av[q].y), fmaxf(av[q].z, av[q].w)));
    mb = fmaxf(mb, fmaxf(fmaxf(bv[q].x, bv[q].y), fmaxf(bv[q].z, bv[q].w)));
  }
  #pragma unroll
  for (int off = 32; off; off >>= 1) {
    ma = fmaxf(ma, __shfl_down(ma, off));
    mb = fmaxf(mb, __shfl_down(mb, off));
  }
  if (lane == 0) { sm.t.red[wv] = ma; sm.t.red[4 + wv] = mb; }
  __syncthreads();
  float fa = fmaxf(fmaxf(sm.t.red[0], sm.t.red[1]), fmaxf(sm.t.red[2], sm.t.red[3]));
  float fb = fmaxf(fmaxf(sm.t.red[4], sm.t.red[5]), fmaxf(sm.t.red[6], sm.t.red[7]));
  float ia = 1.0f / fa, ib = 1.0f / fb;

  #pragma unroll
  for (int q = 0; q < 9; ++q) {          // stage scaled: B row-major, A col-major
    int e = tid*36 + q*4;
    int r = e / 96, k = e - r*96;
    float4 bb = bv[q];
    bb.x *= ib; bb.y *= ib; bb.z *= ib; bb.w *= ib;
    *(float4*)&sm.t.Bs[r*TPAD + k] = bb;
    float4 aa = av[q];
    sm.t.Acs[(k+0)*TPAD + r] = aa.x * ia;
    sm.t.Acs[(k+1)*TPAD + r] = aa.y * ia;
    sm.t.Acs[(k+2)*TPAD + r] = aa.z * ia;
    sm.t.Acs[(k+3)*TPAD + r] = aa.w * ia;
  }
  __syncthreads();

  int tr = tid >> 4, tc = tid & 15;
  int r0 = tr * 6, c0 = cs + tc * 3;
  float acc[6][3];
  #pragma unroll
  for (int i = 0; i < 6; ++i)
    #pragma unroll
    for (int m = 0; m < 3; ++m) acc[i][m] = 0.f;
  for (int k = 0; k < 96; k += 4) {
    float4 a0 = *(const float4*)&sm.t.Acs[(c0+0)*TPAD + k];
    float4 a1 = *(const float4*)&sm.t.Acs[(c0+1)*TPAD + k];
    float4 a2 = *(const float4*)&sm.t.Acs[(c0+2)*TPAD + k];
    #pragma unroll
    for (int i = 0; i < 6; ++i) {
      float4 b = *(const float4*)&sm.t.Bs[(r0+i)*TPAD + k];
      acc[i][0] += b.x*a0.x + b.y*a0.y + b.z*a0.z + b.w*a0.w;
      acc[i][1] += b.x*a1.x + b.y*a1.y + b.z*a1.z + b.w*a1.w;
      acc[i][2] += b.x*a2.x + b.y*a2.y + b.z*a2.z + b.w*a2.w;
    }
  }
  float* op = Tout + (size_t)j * 9216;
  #pragma unroll
  for (int i = 0; i < 6; ++i)
    #pragma unroll
    for (int m = 0; m < 3; ++m)
      stg_f32(&op[(size_t)(r0+i)*96 + c0 + m], acc[i][m]);
  if ((bid & 1) == 0 && tid == 0)
    stg_f32(&Cout[j], Cin[2*j] + Cin[2*j + 1] + __logf(fa) + __logf(fb));
}

// ---------------- mega kernel: flag-pipelined phase graph ------------------
__global__ __launch_bounds__(256, 1) void mega_kernel(
    const float* feats, const float* Wd, const float* bd,
    const float* Wl, const float* Wr, const float* Gl, const float* Gr,
    unsigned short* WcB, const float* bc,
    unsigned short* ht, const float* Wt, const float* bt,
    float* Bband, float* Xn, float* muv, const float* trans,
    const int* tags,
    float* T0, float* T1, float* T2, float* T3, float* T4,
    float* C0, float* C1, float* C2, float* C3, float* C4,
    float* out, unsigned* flags)
{
  __shared__ SmemU sm;
  const int bid = blockIdx.x;
  const int tid = threadIdx.x;
  const int wave = tid >> 6, lane = tid & 63;

  // ============ WcB conversion (blocks 48..255, concurrent with hgemm) =====
  if (bid >= 48) {
    for (int j = (bid - 48)*256 + tid; j < 524288; j += 208*256) {
      int o = j >> 9, k = j & 511;
      float v;
      if (k < 256) v = (o < 256) ? Wl[o*256 + k] : Gl[(o-256)*256 + k];
      else { int k2 = k - 256; v = (o < 256) ? Wr[o*256 + k2] : Gr[(o-256)*256 + k2]; }
      stg_u16(&WcB[j], f2bf(v));
    }
    DRAIN();
    __syncthreads();
    if (tid == 0) atomicAdd(&flags[958*32], 1u);
  }

  if (bid < 192) {
    const int p = bid % 12;
    const int lr = tid >> 3;
    const int c8 = (tid & 7) * 8;
    const int q8 = (lane >> 4) * 8;
    // ============ phase: hgemm (48 blocks; f32 inputs, cvt on the fly) =====
    if (bid < 48) {
      const int p0 = p * 64;
      const int n0 = (bid / 12) * 64;
      f32x4 acc[4];
      #pragma unroll
      for (int i = 0; i < 4; ++i)
        #pragma unroll
        for (int j = 0; j < 4; ++j) acc[i][j] = 0.f;
      F8 fa0[2], fa1[2], fw0[2], fw1[2];
      #pragma unroll
      for (int q = 0; q < 2; ++q) {
        int kb = q * 64;
        fa0[q] = ldf8(feats + (size_t)(p0 + lr)*512 + kb + c8);
        fa1[q] = ldf8(feats + (size_t)(p0 + lr + 32)*512 + kb + c8);
        fw0[q] = ldf8(Wd + (size_t)(n0 + lr)*512 + kb + c8);
        fw1[q] = ldf8(Wd + (size_t)(n0 + lr + 32)*512 + kb + c8);
      }
      #pragma unroll
      for (int kt = 0; kt < 8; ++kt) {
        const int sb = kt & 1;
        *(short8*)(&sm.g.As[sb][lr][c8])      = cvtF8(fa0[sb]);
        *(short8*)(&sm.g.As[sb][lr + 32][c8]) = cvtF8(fa1[sb]);
        *(short8*)(&sm.g.Ws[sb][lr][c8])      = cvtF8(fw0[sb]);
        *(short8*)(&sm.g.Ws[sb][lr + 32][c8]) = cvtF8(fw1[sb]);
        if (kt < 6) {
          int kb = (kt + 2) * 64;
          fa0[sb] = ldf8(feats + (size_t)(p0 + lr)*512 + kb + c8);
          fa1[sb] = ldf8(feats + (size_t)(p0 + lr + 32)*512 + kb + c8);
          fw0[sb] = ldf8(Wd + (size_t)(n0 + lr)*512 + kb + c8);
          fw1[sb] = ldf8(Wd + (size_t)(n0 + lr + 32)*512 + kb + c8);
        }
        KTBAR();
        #pragma unroll
        for (int kk = 0; kk < 2; ++kk) {
          short8 bfr = *(const short8*)(&sm.g.Ws[sb][wave*16 + (lane & 15)][kk*32 + q8]);
          #pragma unroll
          for (int mt = 0; mt < 4; ++mt) {
            short8 afr = *(const short8*)(&sm.g.As[sb][mt*16 + (lane & 15)][kk*32 + q8]);
            acc[mt] = __builtin_amdgcn_mfma_f32_16x16x32_bf16(afr, bfr, acc[mt], 0, 0, 0);
          }
        }
        KTBAR();   // all waves done reading buffer sb before it is overwritten
      }
      int o = n0 + wave*16 + (lane & 15);
      float bias = bd[o];
      #pragma unroll
      for (int mt = 0; mt < 4; ++mt)
        #pragma unroll
        for (int r = 0; r < 4; ++r) {
          int row = p0 + mt*16 + (lane >> 4)*4 + r;
          stg_u16(&ht[row*256 + o], f2bf(acc[mt][r] + bias));
        }
      DRAIN();
      __syncthreads();
      if (tid == 0) atomicAdd(&flags[(0*12 + p)*32], 1u);
    }

    // ============ 7 span iterations: W in regs (once), split-wait staging ===
    const int p0 = p * 64;
    const int n0i = (bid / 12) * 16;
    if (tid == 0) flag_spin(&flags[958*32], 208u);
    __syncthreads();
    short8 wfrag[16];
    {
      const size_t wrow = (size_t)(wave*256 + n0i + (lane & 15)) * 512;
      #pragma unroll
      for (int kt = 0; kt < 8; ++kt)
        #pragma unroll
        for (int kk = 0; kk < 2; ++kk)
          wfrag[kt*2 + kk] = *(const short8*)(WcB + wrow + kt*64 + kk*32 + q8);
    }
    for (int sl = 1; sl <= 7; ++sl) {
      unsigned tgt = (sl == 1) ? 4u : 16u;
      if (tid == 0) flag_spin(&flags[((sl-1)*12 + p)*32], tgt);
      __syncthreads();                          // tile p ready
      const unsigned short* htp = ht + (size_t)(sl - 1) * 196608;
      unsigned short* htn = ht + (size_t)sl * 196608;
      const int Mvalid = 768 - sl;
      short8 areg[16];
      // kt 0..3 (shift=0): rows p0..p0+63, tile p ONLY -> load while thread
      // 64 concurrently waits for tile p+1 (split-wait overlap).
      #pragma unroll
      for (int kt = 0; kt < 4; ++kt) {
        const int kcol = kt * 64;
        areg[kt*2]     = *(const short8*)(htp + (size_t)(p0 + lr)*256 + kcol + c8);
        areg[kt*2 + 1] = *(const short8*)(htp + (size_t)(p0 + lr + 32)*256 + kcol + c8);
      }
      if (tid == 64 && p < 11) flag_spin(&flags[((sl-1)*12 + p + 1)*32], tgt);
      #pragma unroll
      for (int kt = 0; kt < 4; ++kt) {
        *(short8*)(&sm.gi.As8[kt][lr][c8])      = areg[kt*2];
        *(short8*)(&sm.gi.As8[kt][lr + 32][c8]) = areg[kt*2 + 1];
      }
      __syncthreads();                          // p+1 ready AND kt0..3 staged
      // kt 4..7 (shift=1): rows p0+1..p0+64 (touches tile p+1's first row).
      #pragma unroll
      for (int kt = 4; kt < 8; ++kt) {
        const int kcol = (kt & 3) * 64;
        int g0 = p0 + lr + 1;      if (g0 > 767) g0 = 767;
        int g1 = p0 + lr + 33;     if (g1 > 767) g1 = 767;
        areg[kt*2]     = *(const short8*)(htp + (size_t)g0*256 + kcol + c8);
        areg[kt*2 + 1] = *(const short8*)(htp + (size_t)g1*256 + kcol + c8);
      }
      #pragma unroll
      for (int kt = 4; kt < 8; ++kt) {
        *(short8*)(&sm.gi.As8[kt][lr][c8])      = areg[kt*2];
        *(short8*)(&sm.gi.As8[kt][lr + 32][c8]) = areg[kt*2 + 1];
      }
      __syncthreads();
      // MFMA sweep: no barriers, compiler-scheduled lgkmcnt only.
      f32x4 acc[4];
      #pragma unroll
      for (int i = 0; i < 4; ++i)
        #pragma unroll
        for (int j = 0; j < 4; ++j) acc[i][j] = 0.f;
      #pragma unroll
      for (int kt = 0; kt < 8; ++kt) {
        #pragma unroll
        for (int kk = 0; kk < 2; ++kk) {
          #pragma unroll
          for (int mt = 0; mt < 4; ++mt) {
            short8 afr = *(const short8*)(&sm.gi.As8[kt][mt*16 + (lane & 15)][kk*32 + q8]);
            acc[mt] = __builtin_amdgcn_mfma_f32_16x16x32_bf16(afr, wfrag[kt*2 + kk], acc[mt], 0, 0, 0);
          }
        }
      }
      #pragma unroll
      for (int mt = 0; mt < 4; ++mt)
        #pragma unroll
        for (int r = 0; r < 4; ++r)
          sm.gi.Cs[mt*16 + (lane >> 4)*4 + r][wave*16 + (lane & 15)] = acc[mt][r];
      __syncthreads();

      // epilogue: 2 adjacent d-cols per thread, packed u32 stores
      {
        int dl = tid & 7;
        int d0 = n0i + dl*2;
        int cc0 = dl*2;
        float bz0 = bc[d0],       bz1 = bc[d0+1];
        float b00 = bc[256 + d0], b01 = bc[256 + d0 + 1];
        float b10 = bc[512 + d0], b11 = bc[512 + d0 + 1];
        float b20 = bc[768 + d0], b21 = bc[768 + d0 + 1];
        for (int pr = tid >> 3; pr < 64; pr += 32) {
          int pw = p0 + pr;
          if (pw >= Mvalid) continue;
          float z0 = sm.gi.Cs[pr][cc0]      + bz0, z1 = sm.gi.Cs[pr][cc0+1]      + bz1;
          float g00 = sm.gi.Cs[pr][16+cc0]  + b00, g01 = sm.gi.Cs[pr][16+cc0+1]  + b01;
          float g10 = sm.gi.Cs[pr][32+cc0]  + b10, g11 = sm.gi.Cs[pr][32+cc0+1]  + b11;
          float g20 = sm.gi.Cs[pr][48+cc0]  + b20, g21 = sm.gi.Cs[pr][48+cc0+1]  + b21;
          unsigned lv = *(const unsigned*)(htp + (size_t)pw*256 + d0);
          unsigned rv = *(const unsigned*)(htp + (size_t)(pw+1)*256 + d0);
          float l0 = bf2f((short)(lv & 0xffff)), l1 = bf2f((short)(lv >> 16));
          float r0v = bf2f((short)(rv & 0xffff)), r1v = bf2f((short)(rv >> 16));
          float hh0 = 4.f / (1.f + __expf(-z0)) - 2.f;
          float hh1 = 4.f / (1.f + __expf(-z1)) - 2.f;
          float mg0 = fmaxf(g00, fmaxf(g10, g20));
          float mg1 = fmaxf(g01, fmaxf(g11, g21));
          float e00 = __expf(g00 - mg0), e10 = __expf(g10 - mg0), e20 = __expf(g20 - mg0);
          float e01 = __expf(g01 - mg1), e11 = __expf(g11 - mg1), e21 = __expf(g21 - mg1);
          float o0 = (e00*hh0 + e10*l0 + e20*r0v) / (e00 + e10 + e20);
          float o1 = (e01*hh1 + e11*l1 + e21*r1v) / (e01 + e11 + e21);
          unsigned pack = (unsigned)f2bf(o0) | ((unsigned)f2bf(o1) << 16);
          stg_u32((unsigned*)(htn + (size_t)pw*256 + d0), pack);
        }
      }
      DRAIN();
      __syncthreads();
      if (tid == 0) atomicAdd(&flags[(sl*12 + p)*32], 1u);
    }
  }

  // ============ phase: band (768 single-i tasks; 3 per block max) ===========
  for (int i1 = bid; i1 < 768; i1 += 256) {
    const int i = i1 + 1;   // 1..768
    if (tid < 2) {
      int rlo = i - 8; if (rlo < 0) rlo = 0;
      int tlo = rlo >> 6, thi = (i - 1) >> 6;
      int tt = (tid == 0) ? tlo : thi;
      flag_spin(&flags[(7*12 + tt)*32], 16u);
    }
    __syncthreads();
    {
      int k = tid >> 5, cc = (tid & 31) * 8;
      int pr = i - 8 + k;
      short8 v;
      if (pr >= 0) {
        int slx = 7 - k;
        v = *(const short8*)(ht + ((size_t)slx*768 + pr)*256 + cc);
      } else {
        #pragma unroll
        for (int j = 0; j < 8; ++j) v[j] = 0;
      }
      *(short8*)(&sm.bn.rows[k][cc]) = v;
    }
    __syncthreads();
    float res = -1e30f;
    if (tid < 96) {
      int t = tid >> 3, k = tid & 7;
      int pr = i - 8 + k;
      if (pr >= 0) {
        float acc = 0.f;
        for (int dch = 0; dch < 256; dch += 8) {
          float4 wa = *(const float4*)(Wt + t*256 + dch);
          float4 wb = *(const float4*)(Wt + t*256 + dch + 4);
          short8 hv = *(const short8*)(&sm.bn.rows[k][dch]);
          acc += wa.x*bf2f(hv[0]) + wa.y*bf2f(hv[1]) + wa.z*bf2f(hv[2]) + wa.w*bf2f(hv[3])
               + wb.x*bf2f(hv[4]) + wb.y*bf2f(hv[5]) + wb.z*bf2f(hv[6]) + wb.w*bf2f(hv[7]);
        }
        res = acc + bt[t];
      }
      stg_f32(&Bband[(size_t)i*96 + tid], res);
      sm.bn.sred[tid] = res;
    }
    __syncthreads();
    if (tid < 32) {
      float m = fmaxf(sm.bn.sred[tid], fmaxf(sm.bn.sred[tid+32], sm.bn.sred[tid+64]));
      #pragma unroll
      for (int off = 16; off; off >>= 1) m = fmaxf(m, __shfl_down(m, off));
      if (tid == 0) { stg_f32(&muv[i], m); sm.bn.smu = m; }
    }
    __syncthreads();
    if (tid < 96) stg_f32(&Xn[(size_t)i*96 + tid], __expf(res - sm.bn.smu));
    DRAIN();
    __syncthreads();
    if (tid == 0) atomicAdd(&flags[(96 + i1)*32], 1u);
  }
  if (bid >= 240) return;

  // ============ phase: chunkT (240 blocks; 5 per chunk) ============
  {
    const int chunk = bid / 5;
    const int bxx = bid % 5;
    if (tid < 16) flag_spin(&flags[(96 + 16*chunk + tid)*32], 1u);
    __syncthreads();
    if (bxx == 0 && tid == 0) stg_f32(&C0[chunk], 0.f);
    const int a = chunk * 16;
    const int g = lane / 12;
    const int t = lane - g * 12;
    const int cidx = bxx * 20 + wave * 5 + g;
    const bool active = (g < 5) && (cidx < 96);
    const int c = active ? cidx : 95;
    const int s = c / 12, tau = c - s * 12;
    float Etc[12];
    #pragma unroll
    for (int jj = 0; jj < 12; ++jj) Etc[jj] = __expf(trans[jj*12 + t]);
    float NA[8], V[8];
    #pragma unroll
    for (int jj = 0; jj < 8; ++jj) { NA[jj] = 0.f; V[jj] = 0.f; }
    #pragma unroll
    for (int jj = 0; jj < 8; ++jj) if (jj == s) {
      NA[jj] = (t == tau) ? 1.f : 0.f;
      V[jj]  = Etc[tau];
    }
    const int gbb = (g * 12) * 4;
    #pragma unroll
    for (int m = 1; m <= 16; ++m) {
      const float* xr = Xn + (size_t)(a + m) * 96 + t * 8;
      float4 x0 = *(const float4*)xr;
      float4 x1 = *(const float4*)(xr + 4);
      float sf = __expf(-muv[a + m]);
      float na = x0.x*V[0] + x0.y*V[1] + x0.z*V[2] + x0.w*V[3]
               + x1.x*V[4] + x1.y*V[5] + x1.z*V[6] + x1.w*V[7];
      int nai = __float_as_int(na);
      float nb[12];
      #pragma unroll
      for (int jj = 0; jj < 12; ++jj)
        nb[jj] = __int_as_float(__builtin_amdgcn_ds_bpermute(gbb + jj*4, nai));
      float pp0 = nb[0]*Etc[0] + nb[1]*Etc[1] + nb[2]*Etc[2]   + nb[3]*Etc[3];
      float pp1 = nb[4]*Etc[4] + nb[5]*Etc[5] + nb[6]*Etc[6]   + nb[7]*Etc[7];
      float pp2 = nb[8]*Etc[8] + nb[9]*Etc[9] + nb[10]*Etc[10] + nb[11]*Etc[11];
      float v = (pp0 + pp1) + pp2;
      #pragma unroll
      for (int kq = 0; kq < 7; ++kq) { NA[kq] = NA[kq+1]*sf; V[kq] = V[kq+1]*sf; }
      NA[7] = na; V[7] = v;
    }
    if (active) {
      float* dst = T0 + (size_t)chunk * 9216 + c;
      #pragma unroll
      for (int jj = 0; jj < 8; ++jj) stg_f32(&dst[(size_t)(jj*12 + t) * 96], NA[jj]);
    }
    DRAIN();
    __syncthreads();
    if (tid == 0) atomicAdd(&flags[(864 + chunk)*32], 1u);
  }
  if (bid >= 48) return;

  // ============ tree levels with per-output flags ============
  {
    int j = bid >> 1;
    if (tid < 2) flag_spin(&flags[(864 + 2*j + tid)*32], 5u);
    __syncthreads();
    treelevel(sm, T0, C0, T1, C1);       // 48 -> 24
    DRAIN(); __syncthreads();
    if (tid == 0) atomicAdd(&flags[(912 + j)*32], 1u);
  }
  if (bid >= 24) return;
  {
    int j = bid >> 1;
    if (tid < 2) flag_spin(&flags[(912 + 2*j + tid)*32], 2u);
    __syncthreads();
    treelevel(sm, T1, C1, T2, C2);       // 24 -> 12
    DRAIN(); __syncthreads();
    if (tid == 0) atomicAdd(&flags[(936 + j)*32], 1u);
  }
  if (bid >= 12) return;
  {
    int j = bid >> 1;
    if (tid < 2) flag_spin(&flags[(936 + 2*j + tid)*32], 2u);
    __syncthreads();
    treelevel(sm, T2, C2, T3, C3);       // 12 -> 6
    DRAIN(); __syncthreads();
    if (tid == 0) atomicAdd(&flags[(948 + j)*32], 1u);
  }
  if (bid >= 6) return;
  {
    int j = bid >> 1;
    if (tid < 2) flag_spin(&flags[(948 + 2*j + tid)*32], 2u);
    __syncthreads();
    treelevel(sm, T3, C3, T4, C4);       //  6 -> 3
    DRAIN(); __syncthreads();
    if (tid == 0) atomicAdd(&flags[(954 + j)*32], 1u);
  }
  if (bid) return;

  // ============ phase: final (block 0) ============
  {
    if (tid < 3) flag_spin(&flags[(954 + tid)*32], 2u);
    __syncthreads();
    float4 P[9];
    const float* p0p = T4 + tid * 36;
    #pragma unroll
    for (int q = 0; q < 9; ++q) P[q] = *(const float4*)(p0p + q*4);

    float gold = 0.f;
    if (tid < 96) {
      int a = tags[tid*4+0], b = tags[tid*4+1], cc = tags[tid*4+2], d = tags[tid*4+3];
      float v = trans[cc*12 + d];
      int sl = b - a;
      if (sl >= 0 && sl < 8) v += Bband[(size_t)(b+1)*96 + d*8 + (7 - sl)];
      else v += bt[d];
      gold = v;
    }
    float mp = 0.f;
    for (int q = tid; q < 768; q += 256) mp += muv[1 + q];
    #pragma unroll
    for (int off = 32; off; off >>= 1) {
      gold += __shfl_down(gold, off);
      mp   += __shfl_down(mp, off);
    }
    if (lane == 0) { sm.f.red[wave] = gold; sm.f.red[4 + wave] = mp; }

    #pragma unroll
    for (int q = 0; q < 9; ++q) {
      int e = tid*36 + q*4;
      int r = e / 96, k = e - r*96;
      *(float4*)&sm.f.Qs[0][r*TPAD + k] = P[q];
    }
    if (tid < 96) sm.f.vv[0][tid] = (tid == 94) ? 1.f : 0.f;  // onehot(START=84+10)
    __syncthreads();
    float gold_t = sm.f.red[0] + sm.f.red[1] + sm.f.red[2] + sm.f.red[3];
    float musum  = sm.f.red[4] + sm.f.red[5] + sm.f.red[6] + sm.f.red[7];
    float Ct = C4[0] + C4[1] + C4[2];

    #pragma unroll
    for (int s = 0; s < 3; ++s) {
      if (s < 2) {                       // prefetch next matrix during matvec
        const float* pn = T4 + (size_t)(s+1)*9216 + tid*36;
        #pragma unroll
        for (int q = 0; q < 9; ++q) P[q] = *(const float4*)(pn + q*4);
      }
      float acc = 0.f;
      if (tid < 96) {
        const float* Qr = &sm.f.Qs[s & 1][tid * TPAD];
        #pragma unroll
        for (int k = 0; k < 96; k += 4) {
          float4 qv = *(const float4*)(Qr + k);
          float4 zv = *(const float4*)&sm.f.vv[s][k];
          acc += qv.x*zv.x + qv.y*zv.y + qv.z*zv.z + qv.w*zv.w;
        }
      }
      float am = (tid < 96) ? acc : 0.f;
      #pragma unroll
      for (int off = 32; off; off >>= 1) am = fmaxf(am, __shfl_down(am, off));
      if (lane == 0) sm.f.redm[wave] = am;
      __syncthreads();
      float mx = fmaxf(fmaxf(sm.f.redm[0], sm.f.redm[1]), fmaxf(sm.f.redm[2], sm.f.redm[3]));
      Ct += __logf(mx);
      if (tid < 96) sm.f.vv[s+1][tid] = acc / mx;
      if (s < 2) {
        #pragma unroll
        for (int q = 0; q < 9; ++q) {
          int e = tid*36 + q*4;
          int r = e / 96, k = e - r*96;
          *(float4*)&sm.f.Qs[(s+1)&1][r*TPAD + k] = P[q];
        }
      }
      __syncthreads();
    }
    if (tid == 0) {
      float lsum = 0.f;
      #pragma unroll
      for (int t = 0; t < 11; ++t) lsum += __logf(sm.f.vv[3][84 + t]);
      out[0] = lsum + 11.f * (Ct + musum) - gold_t;
    }
  }
}

// ---------------------------------------------------------------------------
extern "C" void kernel_launch(void* const* d_in, const int* in_sizes, int n_in,
                              void* d_out, int out_size, void* d_ws, size_t ws_size,
                              hipStream_t stream)
{
  const float* feats = (const float*)d_in[0];
  const int*   tags  = (const int*)  d_in[1];
  const float* Wd    = (const float*)d_in[2];
  const float* bd    = (const float*)d_in[3];
  const float* Wl    = (const float*)d_in[4];
  const float* bl    = (const float*)d_in[5];
  const float* Wr    = (const float*)d_in[6];
  const float* br    = (const float*)d_in[7];
  const float* Gl    = (const float*)d_in[8];
  const float* bgl   = (const float*)d_in[9];
  const float* Gr    = (const float*)d_in[10];
  const float* bgr   = (const float*)d_in[11];
  const float* Wt    = (const float*)d_in[12];
  const float* bt    = (const float*)d_in[13];
  const float* trans = (const float*)d_in[14];
  float* out = (float*)d_out;

  // Workspace layout: every buffer below is written exactly once inside the
  // mega kernel (with sc1 stores) and never read before written. No overlays.
  char* ws = (char*)d_ws;
  unsigned short* WcB    = (unsigned short*)(ws + 1048576);  // 1024*512 bf16
  float*          bc     = (float*)         (ws + 2097152);  // 1024 f32
  unsigned short* ht     = (unsigned short*)(ws + 2101248);  // 8*768*256 bf16
  float*          Bband  = (float*)         (ws + 5246976);  // 769*96 f32
  float*          Xn     = (float*)         (ws + 5542272);  // 769*96 f32
  float*          muv    = (float*)         (ws + 5837568);  // 769 f32
  float*          T0     = (float*)         (ws + 5841664);  // 48*9216 f32
  float*          T1     = (float*)         (ws + 7611136);  // 24*9216 f32
  float*          T2     = (float*)         (ws + 8495872);  // 12*9216 f32
  float*          T3     = (float*)         (ws + 8938240);  //  6*9216 f32
  float*          T4     = (float*)         (ws + 9159424);  //  3*9216 f32
  float*          C0     = (float*)         (ws + 9270016);  // 48 f32
  float*          C1     = (float*)         (ws + 9270272);  // 24 f32
  float*          C2     = (float*)         (ws + 9270528);  // 12 f32
  float*          C3     = (float*)         (ws + 9270784);  //  6 f32
  float*          C4     = (float*)         (ws + 9271040);  //  3 f32
  unsigned*       flags  = (unsigned*)      (ws + 9271296);  // 959 flags x 32 u32

  prep_kernel<<<124, 256, 0, stream>>>(bl, br, bgl, bgr, bc, flags);
  mega_kernel<<<256, 256, 0, stream>>>(feats, Wd, bd, Wl, Wr, Gl, Gr, WcB, bc,
                                       ht, Wt, bt, Bband, Xn, muv, trans, tags,
                                       T0, T1, T2, T3, T4, C0, C1, C2, C3, C4,
                                       out, flags);
}